// Round 1
// baseline (253.619 us; speedup 1.0000x reference)
//
#include <hip/hip_runtime.h>
#include <math.h>

typedef float f32x4 __attribute__((ext_vector_type(4)));
typedef __bf16 bf16x8 __attribute__((ext_vector_type(8)));
typedef unsigned short u16x8 __attribute__((ext_vector_type(8)));
typedef unsigned short u16x4 __attribute__((ext_vector_type(4)));

#define DEV static __device__ __forceinline__

DEV unsigned short f2bf(float f) {
    unsigned int u = __builtin_bit_cast(unsigned int, f);
    u += 0x7fffu + ((u >> 16) & 1u);   // RNE
    return (unsigned short)(u >> 16);
}

// async global->LDS, 16B per lane; LDS dest is wave-uniform base + lane*16
#define GLD16(gp, lp) __builtin_amdgcn_global_load_lds( \
    (__attribute__((address_space(1))) void*)(gp),      \
    (__attribute__((address_space(3))) void*)(lp), 16, 0, 0)

// ---------------------------------------------------------------- cast x -> bf16
__global__ __launch_bounds__(256) void k_cast(const float* __restrict__ x,
                                              unsigned short* __restrict__ xb) {
    int i = blockIdx.x * 256 + threadIdx.x;
    const float4* p = (const float4*)(x + (size_t)i * 8);
    float4 a = p[0], b = p[1];
    u16x8 o;
    o[0] = f2bf(a.x); o[1] = f2bf(a.y); o[2] = f2bf(a.z); o[3] = f2bf(a.w);
    o[4] = f2bf(b.x); o[5] = f2bf(b.y); o[6] = f2bf(b.z); o[7] = f2bf(b.w);
    *(u16x8*)(xb + (size_t)i * 8) = o;
}

// ------------------------------------------- transpose+cast f32 [R][C] -> bf16 [C][R]
// dst row = rowBase + z*sliceRows + c ; dst leading dim = 1024
__global__ __launch_bounds__(256) void k_transw(const float* __restrict__ src,
                                                unsigned short* __restrict__ dst,
                                                int Cdim, int sliceStride,
                                                int rowBase, int sliceRows) {
    __shared__ unsigned short t[64][68];
    int r0 = blockIdx.x * 64, c0 = blockIdx.y * 64, z = blockIdx.z;
    src += (size_t)z * sliceStride;
    int tid = threadIdx.x;
#pragma unroll
    for (int it = 0; it < 4; ++it) {
        int r = (tid >> 4) + it * 16;
        int c4 = (tid & 15) * 4;
        float4 v = *(const float4*)&src[(size_t)(r0 + r) * Cdim + c0 + c4];
        t[c4 + 0][r] = f2bf(v.x);
        t[c4 + 1][r] = f2bf(v.y);
        t[c4 + 2][r] = f2bf(v.z);
        t[c4 + 3][r] = f2bf(v.w);
    }
    __syncthreads();
#pragma unroll
    for (int it = 0; it < 4; ++it) {
        int c = (tid >> 4) + it * 16;
        int r4 = (tid & 15) * 4;
        u16x4 o;
        o[0] = t[c][r4 + 0]; o[1] = t[c][r4 + 1];
        o[2] = t[c][r4 + 2]; o[3] = t[c][r4 + 3];
        int row = rowBase + z * sliceRows + c0 + c;
        *(u16x4*)&dst[(size_t)row * 1024 + r0 + r4] = o;
    }
}

// ---------------------------------------------------------------- GEMM  C = A * Bt^T
// A [M][Kd] bf16 row-major, Bt [N][Kd] bf16 row-major. 128x128 tile, BK=64, 4 waves.
// STAGE 1: writes Q(scaled bf16), K(bf16), V^T(bf16). STAGE 3: writes f32 + bias.
template <int STAGE>
__global__ __launch_bounds__(256) void k_gemm(const unsigned short* __restrict__ A,
                                              const unsigned short* __restrict__ Bt,
                                              int Kd,
                                              float* __restrict__ outF,
                                              const float* __restrict__ bias,
                                              unsigned short* __restrict__ Qb,
                                              unsigned short* __restrict__ Kb,
                                              unsigned short* __restrict__ Vt) {
    __shared__ unsigned short As[128 * 64] __attribute__((aligned(16)));
    __shared__ unsigned short Bs[128 * 64] __attribute__((aligned(16)));
    const int tid = threadIdx.x, l = tid & 63, w = tid >> 6;
    const int bn = blockIdx.x, bm = blockIdx.y;
    const int wr = w >> 1, wc = w & 1;
    const int g = l >> 4, q = l & 15;
    f32x4 acc[4][4] = {};
    const unsigned short* gA = A + (size_t)(bm * 128 + w * 8 + (l >> 3)) * Kd + (l & 7) * 8;
    const unsigned short* gB = Bt + (size_t)(bn * 128 + w * 8 + (l >> 3)) * Kd + (l & 7) * 8;
    for (int k0 = 0; k0 < Kd; k0 += 64) {
#pragma unroll
        for (int it = 0; it < 4; ++it) {
            GLD16(gA + (size_t)(it * 32) * Kd + k0, &As[(it * 32 + w * 8) * 64]);
            GLD16(gB + (size_t)(it * 32) * Kd + k0, &Bs[(it * 32 + w * 8) * 64]);
        }
        __syncthreads();
#pragma unroll
        for (int ks = 0; ks < 2; ++ks) {
            bf16x8 af[4], bfr[4];
#pragma unroll
            for (int mi = 0; mi < 4; ++mi)
                af[mi] = *(const bf16x8*)&As[(wr * 64 + mi * 16 + q) * 64 + ks * 32 + g * 8];
#pragma unroll
            for (int ni = 0; ni < 4; ++ni)
                bfr[ni] = *(const bf16x8*)&Bs[(wc * 64 + ni * 16 + q) * 64 + ks * 32 + g * 8];
#pragma unroll
            for (int mi = 0; mi < 4; ++mi)
#pragma unroll
                for (int ni = 0; ni < 4; ++ni)
                    acc[mi][ni] = __builtin_amdgcn_mfma_f32_16x16x32_bf16(
                        af[mi], bfr[ni], acc[mi][ni], 0, 0, 0);
        }
        __syncthreads();
    }
#pragma unroll
    for (int mi = 0; mi < 4; ++mi)
#pragma unroll
        for (int ni = 0; ni < 4; ++ni)
#pragma unroll
            for (int r = 0; r < 4; ++r) {
                float c = acc[mi][ni][r];
                int m = bm * 128 + wr * 64 + mi * 16 + g * 4 + r;
                int n = bn * 128 + wc * 64 + ni * 16 + q;
                if (STAGE == 1) {
                    int b = m >> 11, t = m & 2047;
                    int proj = n >> 10, rr = n & 1023, h = rr >> 6, d = rr & 63;
                    int bh = b * 16 + h;
                    if (proj == 0)
                        // fold softmax scale (1/8) and log2(e) into Q
                        Qb[((size_t)bh * 2048 + t) * 64 + d] = f2bf(c * 0.18033688011112042f);
                    else if (proj == 1)
                        Kb[((size_t)bh * 2048 + t) * 64 + d] = f2bf(c);
                    else
                        Vt[((size_t)bh * 64 + d) * 2048 + t] = f2bf(c);
                } else {
                    outF[(size_t)m * 1024 + n] = c + bias[n];
                }
            }
}

// ---------------------------------------------------------------- flash attention
// 4 waves/block, each wave owns 32 q-rows; KV block = 64. Swapped QK^T:
// st = mfma(K_frag, Q^T_frag) -> st[kv][q], lane: q = l&15, kv = f*16 + g*4 + r.
__global__ __launch_bounds__(256) void k_attn(const unsigned short* __restrict__ Qb,
                                              const unsigned short* __restrict__ Kb,
                                              const unsigned short* __restrict__ Vt,
                                              unsigned short* __restrict__ att) {
    __shared__ unsigned short P[4][64][36];  // per-wave P^T staging, padded
    const int tid = threadIdx.x, l = tid & 63, w = tid >> 6;
    const int qblk = blockIdx.x, bh = blockIdx.y;
    const int b = bh >> 4, h = bh & 15;
    const int ql = l & 15, g = l >> 4;
    const int q0 = qblk * 128 + w * 32;
    const unsigned short* Qp = Qb + (size_t)bh * 2048 * 64;
    const unsigned short* Kp = Kb + (size_t)bh * 2048 * 64;
    const unsigned short* Vp = Vt + (size_t)bh * 64 * 2048;

    bf16x8 qf[2][2];
#pragma unroll
    for (int qi = 0; qi < 2; ++qi) {
        int qg = q0 + qi * 16 + ql;
        qf[qi][0] = *(const bf16x8*)(Qp + (size_t)qg * 64 + g * 8);
        qf[qi][1] = *(const bf16x8*)(Qp + (size_t)qg * 64 + 32 + g * 8);
    }
    f32x4 ot[2][4] = {};
    float mrun[2] = {-1e30f, -1e30f}, lrun[2] = {0.f, 0.f};
    const int nkv = (q0 + 95) >> 6;

    for (int kb = 0; kb < nkv; ++kb) {
        const int kvb = kb * 64;
        f32x4 st[2][4] = {};
#pragma unroll
        for (int f = 0; f < 4; ++f) {
            bf16x8 kf0 = *(const bf16x8*)(Kp + (size_t)(kvb + f * 16 + ql) * 64 + g * 8);
            bf16x8 kf1 = *(const bf16x8*)(Kp + (size_t)(kvb + f * 16 + ql) * 64 + 32 + g * 8);
#pragma unroll
            for (int qi = 0; qi < 2; ++qi) {
                st[qi][f] = __builtin_amdgcn_mfma_f32_16x16x32_bf16(kf0, qf[qi][0], st[qi][f], 0, 0, 0);
                st[qi][f] = __builtin_amdgcn_mfma_f32_16x16x32_bf16(kf1, qf[qi][1], st[qi][f], 0, 0, 0);
            }
        }
        if (kb == nkv - 1) {  // diagonal block: causal mask
#pragma unroll
            for (int qi = 0; qi < 2; ++qi) {
                int qg = q0 + qi * 16 + ql;
#pragma unroll
                for (int f = 0; f < 4; ++f)
#pragma unroll
                    for (int r = 0; r < 4; ++r)
                        if (kvb + f * 16 + g * 4 + r > qg) st[qi][f][r] = -1e30f;
            }
        }
#pragma unroll
        for (int qi = 0; qi < 2; ++qi) {
            float pmax = -1e30f;
#pragma unroll
            for (int f = 0; f < 4; ++f)
#pragma unroll
                for (int r = 0; r < 4; ++r) pmax = fmaxf(pmax, st[qi][f][r]);
            pmax = fmaxf(pmax, __shfl_xor(pmax, 16));
            pmax = fmaxf(pmax, __shfl_xor(pmax, 32));
            float mnew = fmaxf(mrun[qi], pmax);
            float corr = exp2f(mrun[qi] - mnew);
            float psum = 0.f;
#pragma unroll
            for (int f = 0; f < 4; ++f)
#pragma unroll
                for (int r = 0; r < 4; ++r) {
                    float p = exp2f(st[qi][f][r] - mnew);
                    psum += p;
                    P[w][f * 16 + g * 4 + r][qi * 16 + ql] = f2bf(p);
                }
            psum += __shfl_xor(psum, 16);
            psum += __shfl_xor(psum, 32);
            lrun[qi] = lrun[qi] * corr + psum;
#pragma unroll
            for (int f = 0; f < 4; ++f) ot[qi][f] *= corr;
            mrun[qi] = mnew;
        }
        // cross-lane LDS visibility within the wave (no barrier: waves have
        // different causal trip counts)
        asm volatile("s_waitcnt lgkmcnt(0)" ::: "memory");
#pragma unroll
        for (int dc = 0; dc < 2; ++dc) {
            bf16x8 pf[2];
#pragma unroll
            for (int qi = 0; qi < 2; ++qi) {
                u16x8 pu;
#pragma unroll
                for (int i = 0; i < 8; ++i) pu[i] = P[w][dc * 32 + g * 8 + i][qi * 16 + ql];
                pf[qi] = __builtin_bit_cast(bf16x8, pu);
            }
#pragma unroll
            for (int f = 0; f < 4; ++f) {
                bf16x8 vf = *(const bf16x8*)(Vp + (size_t)(f * 16 + ql) * 2048 + kvb + dc * 32 + g * 8);
#pragma unroll
                for (int qi = 0; qi < 2; ++qi)
                    ot[qi][f] = __builtin_amdgcn_mfma_f32_16x16x32_bf16(vf, pf[qi], ot[qi][f], 0, 0, 0);
            }
        }
    }
#pragma unroll
    for (int qi = 0; qi < 2; ++qi) {
        float inv = 1.f / lrun[qi];
        int qg = q0 + qi * 16 + ql;
        unsigned short* ap = att + ((size_t)(b * 2048 + qg)) * 1024 + h * 64;
#pragma unroll
        for (int f = 0; f < 4; ++f)
#pragma unroll
            for (int r = 0; r < 4; ++r)
                ap[f * 16 + g * 4 + r] = f2bf(ot[qi][f][r] * inv);
    }
}

extern "C" void kernel_launch(void* const* d_in, const int* in_sizes, int n_in,
                              void* d_out, int out_size, void* d_ws, size_t ws_size,
                              hipStream_t stream) {
    const float* x = (const float*)d_in[0];
    // d_in[1] = attention_mask: causal tril by construction -> hard-coded
    const float* wq = (const float*)d_in[2];
    const float* wk = (const float*)d_in[3];
    const float* wv = (const float*)d_in[4];
    const float* wproj = (const float*)d_in[5];
    const float* bproj = (const float*)d_in[6];
    float* out = (float*)d_out;

    char* ws = (char*)d_ws;
    unsigned short* xb     = (unsigned short*)(ws);               // 8 MB [4096][1024]
    unsigned short* WqkvT  = (unsigned short*)(ws + (8u << 20));  // 6 MB [3072][1024]
    unsigned short* WprojT = (unsigned short*)(ws + (14u << 20)); // 2 MB [1024][1024]
    unsigned short* Qb     = (unsigned short*)(ws + (16u << 20)); // 8 MB [32][2048][64]
    unsigned short* Kb     = (unsigned short*)(ws + (24u << 20)); // 8 MB [32][2048][64]
    unsigned short* Vt     = (unsigned short*)(ws + (32u << 20)); // 8 MB [32][64][2048]
    unsigned short* att    = xb;  // reuse: xb dead after gemm1   // 8 MB [4096][1024]

    k_cast<<<2048, 256, 0, stream>>>(x, xb);
    k_transw<<<dim3(16, 1, 16), 256, 0, stream>>>(wq, WqkvT, 64, 1024 * 64, 0, 64);
    k_transw<<<dim3(16, 1, 16), 256, 0, stream>>>(wk, WqkvT, 64, 1024 * 64, 1024, 64);
    k_transw<<<dim3(16, 1, 16), 256, 0, stream>>>(wv, WqkvT, 64, 1024 * 64, 2048, 64);
    k_transw<<<dim3(16, 16, 1), 256, 0, stream>>>(wproj, WprojT, 1024, 0, 0, 0);
    k_gemm<1><<<dim3(24, 32), 256, 0, stream>>>(xb, WqkvT, 1024, nullptr, nullptr, Qb, Kb, Vt);
    k_attn<<<dim3(16, 32), 256, 0, stream>>>(Qb, Kb, Vt, att);
    k_gemm<3><<<dim3(8, 32), 256, 0, stream>>>(att, WprojT, 1024, out, bproj, nullptr, nullptr, nullptr);
}

// Round 2
// 228.442 us; speedup vs baseline: 1.1102x; 1.1102x over previous
//
#include <hip/hip_runtime.h>
#include <math.h>

typedef float f32x4 __attribute__((ext_vector_type(4)));
typedef __bf16 bf16x8 __attribute__((ext_vector_type(8)));
typedef unsigned short u16x8 __attribute__((ext_vector_type(8)));
typedef unsigned short u16x4 __attribute__((ext_vector_type(4)));

#define DEV static __device__ __forceinline__

DEV unsigned short f2bf(float f) {
    unsigned int u = __builtin_bit_cast(unsigned int, f);
    u += 0x7fffu + ((u >> 16) & 1u);   // RNE
    return (unsigned short)(u >> 16);
}

// async global->LDS, 16B per lane; LDS dest is wave-uniform base + lane*16
#define GLD16(gp, lp) __builtin_amdgcn_global_load_lds( \
    (__attribute__((address_space(1))) void*)(gp),      \
    (__attribute__((address_space(3))) void*)(lp), 16, 0, 0)

// ---------------------------------------------------------------- cast x -> bf16
__global__ __launch_bounds__(256) void k_cast(const float* __restrict__ x,
                                              unsigned short* __restrict__ xb) {
    int i = blockIdx.x * 256 + threadIdx.x;
    const float4* p = (const float4*)(x + (size_t)i * 8);
    float4 a = p[0], b = p[1];
    u16x8 o;
    o[0] = f2bf(a.x); o[1] = f2bf(a.y); o[2] = f2bf(a.z); o[3] = f2bf(a.w);
    o[4] = f2bf(b.x); o[5] = f2bf(b.y); o[6] = f2bf(b.z); o[7] = f2bf(b.w);
    *(u16x8*)(xb + (size_t)i * 8) = o;
}

// ------------------------------------------- transpose+cast f32 [R][C] -> bf16 [C][R]
__global__ __launch_bounds__(256) void k_transw(const float* __restrict__ src,
                                                unsigned short* __restrict__ dst,
                                                int Cdim, int sliceStride,
                                                int rowBase, int sliceRows) {
    __shared__ unsigned short t[64][68];
    int r0 = blockIdx.x * 64, c0 = blockIdx.y * 64, z = blockIdx.z;
    src += (size_t)z * sliceStride;
    int tid = threadIdx.x;
#pragma unroll
    for (int it = 0; it < 4; ++it) {
        int r = (tid >> 4) + it * 16;
        int c4 = (tid & 15) * 4;
        float4 v = *(const float4*)&src[(size_t)(r0 + r) * Cdim + c0 + c4];
        t[c4 + 0][r] = f2bf(v.x);
        t[c4 + 1][r] = f2bf(v.y);
        t[c4 + 2][r] = f2bf(v.z);
        t[c4 + 3][r] = f2bf(v.w);
    }
    __syncthreads();
#pragma unroll
    for (int it = 0; it < 4; ++it) {
        int c = (tid >> 4) + it * 16;
        int r4 = (tid & 15) * 4;
        u16x4 o;
        o[0] = t[c][r4 + 0]; o[1] = t[c][r4 + 1];
        o[2] = t[c][r4 + 2]; o[3] = t[c][r4 + 3];
        int row = rowBase + z * sliceRows + c0 + c;
        *(u16x4*)&dst[(size_t)row * 1024 + r0 + r4] = o;
    }
}

// ---------------------------------------------------------------- GEMM  C = A * Bt^T
template <int STAGE>
__global__ __launch_bounds__(256) void k_gemm(const unsigned short* __restrict__ A,
                                              const unsigned short* __restrict__ Bt,
                                              int Kd,
                                              float* __restrict__ outF,
                                              const float* __restrict__ bias,
                                              unsigned short* __restrict__ Qb,
                                              unsigned short* __restrict__ Kb,
                                              unsigned short* __restrict__ Vt) {
    __shared__ unsigned short As[128 * 64] __attribute__((aligned(16)));
    __shared__ unsigned short Bs[128 * 64] __attribute__((aligned(16)));
    const int tid = threadIdx.x, l = tid & 63, w = tid >> 6;
    const int bn = blockIdx.x, bm = blockIdx.y;
    const int wr = w >> 1, wc = w & 1;
    const int g = l >> 4, q = l & 15;
    f32x4 acc[4][4] = {};
    const unsigned short* gA = A + (size_t)(bm * 128 + w * 8 + (l >> 3)) * Kd + (l & 7) * 8;
    const unsigned short* gB = Bt + (size_t)(bn * 128 + w * 8 + (l >> 3)) * Kd + (l & 7) * 8;
    for (int k0 = 0; k0 < Kd; k0 += 64) {
#pragma unroll
        for (int it = 0; it < 4; ++it) {
            GLD16(gA + (size_t)(it * 32) * Kd + k0, &As[(it * 32 + w * 8) * 64]);
            GLD16(gB + (size_t)(it * 32) * Kd + k0, &Bs[(it * 32 + w * 8) * 64]);
        }
        __syncthreads();
#pragma unroll
        for (int ks = 0; ks < 2; ++ks) {
            bf16x8 af[4], bfr[4];
#pragma unroll
            for (int mi = 0; mi < 4; ++mi)
                af[mi] = *(const bf16x8*)&As[(wr * 64 + mi * 16 + q) * 64 + ks * 32 + g * 8];
#pragma unroll
            for (int ni = 0; ni < 4; ++ni)
                bfr[ni] = *(const bf16x8*)&Bs[(wc * 64 + ni * 16 + q) * 64 + ks * 32 + g * 8];
#pragma unroll
            for (int mi = 0; mi < 4; ++mi)
#pragma unroll
                for (int ni = 0; ni < 4; ++ni)
                    acc[mi][ni] = __builtin_amdgcn_mfma_f32_16x16x32_bf16(
                        af[mi], bfr[ni], acc[mi][ni], 0, 0, 0);
        }
        __syncthreads();
    }
#pragma unroll
    for (int mi = 0; mi < 4; ++mi)
#pragma unroll
        for (int ni = 0; ni < 4; ++ni)
#pragma unroll
            for (int r = 0; r < 4; ++r) {
                float c = acc[mi][ni][r];
                int m = bm * 128 + wr * 64 + mi * 16 + g * 4 + r;
                int n = bn * 128 + wc * 64 + ni * 16 + q;
                if (STAGE == 1) {
                    int b = m >> 11, t = m & 2047;
                    int proj = n >> 10, rr = n & 1023, h = rr >> 6, d = rr & 63;
                    int bh = b * 16 + h;
                    if (proj == 0)
                        Qb[((size_t)bh * 2048 + t) * 64 + d] = f2bf(c * 0.18033688011112042f);
                    else if (proj == 1)
                        Kb[((size_t)bh * 2048 + t) * 64 + d] = f2bf(c);
                    else
                        Vt[((size_t)bh * 64 + d) * 2048 + t] = f2bf(c);
                } else {
                    outF[(size_t)m * 1024 + n] = c + bias[n];
                }
            }
}

// ---------------------------------------------------------------- flash attention
// 8 waves/block, 16 q-rows per wave. Complementary tile pairing for causal
// load balance: waves 0-3 work tile j (rows j*64..), waves 4-7 work tile 31-j.
// Every block does exactly 132 wave-iterations -> zero tail imbalance.
// Swapped QK^T: st = mfma(K, Q^T) -> st[kv][q]; q = l&15, kv = f*16+g*4+r.
// P staged per-wave in LDS as [q][kv] (stride 72 halves) -> b64 writes, b128 reads.
__global__ __launch_bounds__(512) void k_attn(const unsigned short* __restrict__ Qb,
                                              const unsigned short* __restrict__ Kb,
                                              const unsigned short* __restrict__ Vt,
                                              unsigned short* __restrict__ att) {
    __shared__ unsigned short P[8][16][72];  // per-wave P staging [q][kv], padded
    const int tid = threadIdx.x, l = tid & 63, w = tid >> 6;
    const int jb = blockIdx.x, bh = blockIdx.y;
    const int b = bh >> 4, h = bh & 15;
    const int ql = l & 15, g = l >> 4;
    const int tile = (w < 4) ? jb : (31 - jb);
    const int q0 = tile * 64 + (w & 3) * 16;
    const int qg = q0 + ql;
    const unsigned short* Qp = Qb + (size_t)bh * 2048 * 64;
    const unsigned short* Kp = Kb + (size_t)bh * 2048 * 64;
    const unsigned short* Vp = Vt + (size_t)bh * 64 * 2048;

    bf16x8 qf[2];
    qf[0] = *(const bf16x8*)(Qp + (size_t)qg * 64 + g * 8);
    qf[1] = *(const bf16x8*)(Qp + (size_t)qg * 64 + 32 + g * 8);

    f32x4 ot[4] = {};
    float mrun = -1e30f, lrun = 0.f;
    const int nkv = (q0 + 79) >> 6;

    for (int kb = 0; kb < nkv; ++kb) {
        const int kvb = kb * 64;
        f32x4 st[4] = {};
        bf16x8 kf0[4], kf1[4];
#pragma unroll
        for (int f = 0; f < 4; ++f) {
            kf0[f] = *(const bf16x8*)(Kp + (size_t)(kvb + f * 16 + ql) * 64 + g * 8);
            kf1[f] = *(const bf16x8*)(Kp + (size_t)(kvb + f * 16 + ql) * 64 + 32 + g * 8);
        }
        __builtin_amdgcn_s_setprio(1);
#pragma unroll
        for (int f = 0; f < 4; ++f) {
            st[f] = __builtin_amdgcn_mfma_f32_16x16x32_bf16(kf0[f], qf[0], st[f], 0, 0, 0);
            st[f] = __builtin_amdgcn_mfma_f32_16x16x32_bf16(kf1[f], qf[1], st[f], 0, 0, 0);
        }
        __builtin_amdgcn_s_setprio(0);
        if (kb == nkv - 1) {  // diagonal block: causal mask
#pragma unroll
            for (int f = 0; f < 4; ++f)
#pragma unroll
                for (int r = 0; r < 4; ++r)
                    if (kvb + f * 16 + g * 4 + r > qg) st[f][r] = -1e30f;
        }
        float pmax = -1e30f;
#pragma unroll
        for (int f = 0; f < 4; ++f)
#pragma unroll
            for (int r = 0; r < 4; ++r) pmax = fmaxf(pmax, st[f][r]);
        pmax = fmaxf(pmax, __shfl_xor(pmax, 16));
        pmax = fmaxf(pmax, __shfl_xor(pmax, 32));
        float mnew = fmaxf(mrun, pmax);
        float corr = __builtin_amdgcn_exp2f(mrun - mnew);
        float psum = 0.f;
#pragma unroll
        for (int f = 0; f < 4; ++f) {
            u16x4 pk;
#pragma unroll
            for (int r = 0; r < 4; ++r) {
                float p = __builtin_amdgcn_exp2f(st[f][r] - mnew);
                psum += p;
                pk[r] = f2bf(p);
            }
            *(u16x4*)&P[w][ql][f * 16 + g * 4] = pk;  // b64 write
        }
        psum += __shfl_xor(psum, 16);
        psum += __shfl_xor(psum, 32);
        lrun = lrun * corr + psum;
#pragma unroll
        for (int f = 0; f < 4; ++f) ot[f] *= corr;
        mrun = mnew;
        // wave-internal cross-lane LDS visibility (no barrier; waves independent)
        asm volatile("s_waitcnt lgkmcnt(0)" ::: "memory");
#pragma unroll
        for (int dc = 0; dc < 2; ++dc) {
            bf16x8 pf = *(const bf16x8*)&P[w][ql][dc * 32 + g * 8];  // b128 read
            __builtin_amdgcn_s_setprio(1);
#pragma unroll
            for (int f = 0; f < 4; ++f) {
                bf16x8 vf = *(const bf16x8*)(Vp + (size_t)(f * 16 + ql) * 2048 + kvb + dc * 32 + g * 8);
                ot[f] = __builtin_amdgcn_mfma_f32_16x16x32_bf16(vf, pf, ot[f], 0, 0, 0);
            }
            __builtin_amdgcn_s_setprio(0);
        }
    }
    float inv = 1.f / lrun;
    unsigned short* ap = att + ((size_t)(b * 2048 + qg)) * 1024 + h * 64;
#pragma unroll
    for (int f = 0; f < 4; ++f) {
        u16x4 o;
#pragma unroll
        for (int r = 0; r < 4; ++r) o[r] = f2bf(ot[f][r] * inv);
        *(u16x4*)&ap[f * 16 + g * 4] = o;
    }
}

extern "C" void kernel_launch(void* const* d_in, const int* in_sizes, int n_in,
                              void* d_out, int out_size, void* d_ws, size_t ws_size,
                              hipStream_t stream) {
    const float* x = (const float*)d_in[0];
    const float* wq = (const float*)d_in[2];
    const float* wk = (const float*)d_in[3];
    const float* wv = (const float*)d_in[4];
    const float* wproj = (const float*)d_in[5];
    const float* bproj = (const float*)d_in[6];
    float* out = (float*)d_out;

    char* ws = (char*)d_ws;
    unsigned short* xb     = (unsigned short*)(ws);               // 8 MB [4096][1024]
    unsigned short* WqkvT  = (unsigned short*)(ws + (8u << 20));  // 6 MB [3072][1024]
    unsigned short* WprojT = (unsigned short*)(ws + (14u << 20)); // 2 MB [1024][1024]
    unsigned short* Qb     = (unsigned short*)(ws + (16u << 20)); // 8 MB [32][2048][64]
    unsigned short* Kb     = (unsigned short*)(ws + (24u << 20)); // 8 MB [32][2048][64]
    unsigned short* Vt     = (unsigned short*)(ws + (32u << 20)); // 8 MB [32][64][2048]
    unsigned short* att    = xb;  // reuse: xb dead after gemm1   // 8 MB [4096][1024]

    k_cast<<<2048, 256, 0, stream>>>(x, xb);
    k_transw<<<dim3(16, 1, 16), 256, 0, stream>>>(wq, WqkvT, 64, 1024 * 64, 0, 64);
    k_transw<<<dim3(16, 1, 16), 256, 0, stream>>>(wk, WqkvT, 64, 1024 * 64, 1024, 64);
    k_transw<<<dim3(16, 1, 16), 256, 0, stream>>>(wv, WqkvT, 64, 1024 * 64, 2048, 64);
    k_transw<<<dim3(16, 16, 1), 256, 0, stream>>>(wproj, WprojT, 1024, 0, 0, 0);
    k_gemm<1><<<dim3(24, 32), 256, 0, stream>>>(xb, WqkvT, 1024, nullptr, nullptr, Qb, Kb, Vt);
    k_attn<<<dim3(16, 32), 512, 0, stream>>>(Qb, Kb, Vt, att);
    k_gemm<3><<<dim3(8, 32), 256, 0, stream>>>(att, WprojT, 1024, out, bproj, nullptr, nullptr, nullptr);
}

// Round 3
// 158.811 us; speedup vs baseline: 1.5970x; 1.4384x over previous
//
#include <hip/hip_runtime.h>
#include <math.h>

typedef float f32x4 __attribute__((ext_vector_type(4)));
typedef __bf16 bf16x8 __attribute__((ext_vector_type(8)));
typedef unsigned short u16x8 __attribute__((ext_vector_type(8)));
typedef unsigned short u16x4 __attribute__((ext_vector_type(4)));

#define DEV static __device__ __forceinline__

DEV unsigned short f2bf(float f) {
    unsigned int u = __builtin_bit_cast(unsigned int, f);
    u += 0x7fffu + ((u >> 16) & 1u);   // RNE
    return (unsigned short)(u >> 16);
}

// async global->LDS, 16B per lane; LDS dest is wave-uniform base + lane*16
#define GLD16(gp, lp) __builtin_amdgcn_global_load_lds( \
    (__attribute__((address_space(1))) void*)(gp),      \
    (__attribute__((address_space(3))) void*)(lp), 16, 0, 0)

// ---------------------------------------------------------------- cast x -> bf16
__global__ __launch_bounds__(256) void k_cast(const float* __restrict__ x,
                                              unsigned short* __restrict__ xb) {
    int i = blockIdx.x * 256 + threadIdx.x;
    const float4* p = (const float4*)(x + (size_t)i * 8);
    float4 a = p[0], b = p[1];
    u16x8 o;
    o[0] = f2bf(a.x); o[1] = f2bf(a.y); o[2] = f2bf(a.z); o[3] = f2bf(a.w);
    o[4] = f2bf(b.x); o[5] = f2bf(b.y); o[6] = f2bf(b.z); o[7] = f2bf(b.w);
    *(u16x8*)(xb + (size_t)i * 8) = o;
}

// ------------------------------------------- transpose+cast f32 [R][C] -> bf16 [C][R]
__global__ __launch_bounds__(256) void k_transw(const float* __restrict__ src,
                                                unsigned short* __restrict__ dst,
                                                int Cdim, int sliceStride,
                                                int rowBase, int sliceRows) {
    __shared__ unsigned short t[64][68];
    int r0 = blockIdx.x * 64, c0 = blockIdx.y * 64, z = blockIdx.z;
    src += (size_t)z * sliceStride;
    int tid = threadIdx.x;
#pragma unroll
    for (int it = 0; it < 4; ++it) {
        int r = (tid >> 4) + it * 16;
        int c4 = (tid & 15) * 4;
        float4 v = *(const float4*)&src[(size_t)(r0 + r) * Cdim + c0 + c4];
        t[c4 + 0][r] = f2bf(v.x);
        t[c4 + 1][r] = f2bf(v.y);
        t[c4 + 2][r] = f2bf(v.z);
        t[c4 + 3][r] = f2bf(v.w);
    }
    __syncthreads();
#pragma unroll
    for (int it = 0; it < 4; ++it) {
        int c = (tid >> 4) + it * 16;
        int r4 = (tid & 15) * 4;
        u16x4 o;
        o[0] = t[c][r4 + 0]; o[1] = t[c][r4 + 1];
        o[2] = t[c][r4 + 2]; o[3] = t[c][r4 + 3];
        int row = rowBase + z * sliceRows + c0 + c;
        *(u16x4*)&dst[(size_t)row * 1024 + r0 + r4] = o;
    }
}

// ---------------------------------------------------------------- GEMM  C = A * Bt^T
template <int STAGE>
__global__ __launch_bounds__(256) void k_gemm(const unsigned short* __restrict__ A,
                                              const unsigned short* __restrict__ Bt,
                                              int Kd,
                                              float* __restrict__ outF,
                                              const float* __restrict__ bias,
                                              unsigned short* __restrict__ Qb,
                                              unsigned short* __restrict__ Kb,
                                              unsigned short* __restrict__ Vt) {
    __shared__ unsigned short As[128 * 64] __attribute__((aligned(16)));
    __shared__ unsigned short Bs[128 * 64] __attribute__((aligned(16)));
    const int tid = threadIdx.x, l = tid & 63, w = tid >> 6;
    const int bn = blockIdx.x, bm = blockIdx.y;
    const int wr = w >> 1, wc = w & 1;
    const int g = l >> 4, q = l & 15;
    f32x4 acc[4][4] = {};
    const unsigned short* gA = A + (size_t)(bm * 128 + w * 8 + (l >> 3)) * Kd + (l & 7) * 8;
    const unsigned short* gB = Bt + (size_t)(bn * 128 + w * 8 + (l >> 3)) * Kd + (l & 7) * 8;
    for (int k0 = 0; k0 < Kd; k0 += 64) {
#pragma unroll
        for (int it = 0; it < 4; ++it) {
            GLD16(gA + (size_t)(it * 32) * Kd + k0, &As[(it * 32 + w * 8) * 64]);
            GLD16(gB + (size_t)(it * 32) * Kd + k0, &Bs[(it * 32 + w * 8) * 64]);
        }
        __syncthreads();
#pragma unroll
        for (int ks = 0; ks < 2; ++ks) {
            bf16x8 af[4], bfr[4];
#pragma unroll
            for (int mi = 0; mi < 4; ++mi)
                af[mi] = *(const bf16x8*)&As[(wr * 64 + mi * 16 + q) * 64 + ks * 32 + g * 8];
#pragma unroll
            for (int ni = 0; ni < 4; ++ni)
                bfr[ni] = *(const bf16x8*)&Bs[(wc * 64 + ni * 16 + q) * 64 + ks * 32 + g * 8];
#pragma unroll
            for (int mi = 0; mi < 4; ++mi)
#pragma unroll
                for (int ni = 0; ni < 4; ++ni)
                    acc[mi][ni] = __builtin_amdgcn_mfma_f32_16x16x32_bf16(
                        af[mi], bfr[ni], acc[mi][ni], 0, 0, 0);
        }
        __syncthreads();
    }
#pragma unroll
    for (int mi = 0; mi < 4; ++mi)
#pragma unroll
        for (int ni = 0; ni < 4; ++ni)
#pragma unroll
            for (int r = 0; r < 4; ++r) {
                float c = acc[mi][ni][r];
                int m = bm * 128 + wr * 64 + mi * 16 + g * 4 + r;
                int n = bn * 128 + wc * 64 + ni * 16 + q;
                if (STAGE == 1) {
                    int b = m >> 11, t = m & 2047;
                    int proj = n >> 10, rr = n & 1023, h = rr >> 6, d = rr & 63;
                    int bh = b * 16 + h;
                    if (proj == 0)
                        Qb[((size_t)bh * 2048 + t) * 64 + d] = f2bf(c * 0.18033688011112042f);
                    else if (proj == 1)
                        Kb[((size_t)bh * 2048 + t) * 64 + d] = f2bf(c);
                    else
                        Vt[((size_t)bh * 64 + d) * 2048 + t] = f2bf(c);
                } else {
                    outF[(size_t)m * 1024 + n] = c + bias[n];
                }
            }
}

// ---------------------------------------------------------------- flash attention
// Cooperative: 8 waves/block, each wave owns 16 q-rows of a 128-row q-tile.
// K and V tiles (64x64 bf16) staged in LDS via global_load_lds, double-buffered,
// shared by all 8 waves. XOR pre-swizzle on the GLOBAL source (LDS stays linear,
// m173 pattern): physical chunk pc at row r holds logical chunk pc^(r&7), so the
// stride-128B ds_read_b128 fragment reads are ~conflict-free.
// Causal balance: block processes q-tile pair (qt, 15-qt) -> exactly 34 KV-tile
// iterations per block; grid 8x32 = 256 blocks = 1 block/CU.
// Swapped QK^T: st = mfma(K, Q^T) -> st[kv][q]; q = l&15, kv = f*16+g*4+r.
__global__ __launch_bounds__(512) void k_attn(const unsigned short* __restrict__ Qb,
                                              const unsigned short* __restrict__ Kb,
                                              const unsigned short* __restrict__ Vt,
                                              unsigned short* __restrict__ att) {
    __shared__ unsigned short Ks[2][4096] __attribute__((aligned(16)));  // [buf][64r][64]
    __shared__ unsigned short Vs[2][4096] __attribute__((aligned(16)));  // [buf][64d][64]
    __shared__ unsigned short P[8][16][72];  // per-wave P staging [q][kv], padded
    const int tid = threadIdx.x, l = tid & 63, w = tid >> 6;
    const int pj = blockIdx.x, bh = blockIdx.y;
    const int b = bh >> 4, h = bh & 15;
    const int ql = l & 15, g = l >> 4;
    const unsigned short* Qp = Qb + (size_t)bh * 2048 * 64;
    const unsigned short* Kp = Kb + (size_t)bh * 2048 * 64;
    const unsigned short* Vp = Vt + (size_t)bh * 64 * 2048;

    // staging geometry: thread stages 16B at LDS row srow, physical chunk l&7;
    // global source chunk = (l&7) ^ (srow&7)  (srow&7 == l>>3 since w*8%8==0)
    const int srow = w * 8 + (l >> 3);
    const int schk = (l & 7) ^ (l >> 3);
    const unsigned short* gK0 = Kp + (size_t)srow * 64 + schk * 8;
    const unsigned short* gV0 = Vp + (size_t)srow * 2048 + schk * 8;

#define ATT_STAGE(buf, kvb) do {                                   \
        GLD16(gK0 + (size_t)(kvb) * 64, &Ks[buf][w * 512]);        \
        GLD16(gV0 + (kvb), &Vs[buf][w * 512]);                     \
    } while (0)

    for (int ph = 0; ph < 2; ++ph) {
        const int qt = ph ? (15 - pj) : pj;
        const int q0w = qt * 128 + w * 16;
        const int qg = q0w + ql;
        const int nkv = 2 * qt + 2;
        const int kbd = 2 * qt + (w >> 2);  // this wave's diagonal tile index

        bf16x8 qf0 = *(const bf16x8*)(Qp + (size_t)qg * 64 + g * 8);
        bf16x8 qf1 = *(const bf16x8*)(Qp + (size_t)qg * 64 + 32 + g * 8);
        f32x4 ot[4] = {};
        float mrun = -1e30f, lrun = 0.f;

        ATT_STAGE(0, 0);
        asm volatile("s_waitcnt vmcnt(0)" ::: "memory");
        __syncthreads();
        int cur = 0;

        for (int kb = 0; kb < nkv; ++kb) {
            if (kb + 1 < nkv) ATT_STAGE(cur ^ 1, (kb + 1) * 64);  // prefetch next
            if (kb <= kbd) {
                const unsigned short* Kt = &Ks[cur][0];
                const unsigned short* Vtl = &Vs[cur][0];
                f32x4 st[4] = {};
                bf16x8 kf0[4], kf1[4];
#pragma unroll
                for (int f = 0; f < 4; ++f) {
                    int rk = f * 16 + ql, sw = rk & 7;
                    kf0[f] = *(const bf16x8*)&Kt[rk * 64 + ((g ^ sw) * 8)];
                    kf1[f] = *(const bf16x8*)&Kt[rk * 64 + (((g + 4) ^ sw) * 8)];
                }
                __builtin_amdgcn_s_setprio(1);
#pragma unroll
                for (int f = 0; f < 4; ++f) {
                    st[f] = __builtin_amdgcn_mfma_f32_16x16x32_bf16(kf0[f], qf0, st[f], 0, 0, 0);
                    st[f] = __builtin_amdgcn_mfma_f32_16x16x32_bf16(kf1[f], qf1, st[f], 0, 0, 0);
                }
                __builtin_amdgcn_s_setprio(0);
                if (kb == kbd) {  // diagonal tile: causal mask
                    const int kvb = kb * 64;
#pragma unroll
                    for (int f = 0; f < 4; ++f)
#pragma unroll
                        for (int r = 0; r < 4; ++r)
                            if (kvb + f * 16 + g * 4 + r > qg) st[f][r] = -1e30f;
                }
                float pmax = -1e30f;
#pragma unroll
                for (int f = 0; f < 4; ++f)
#pragma unroll
                    for (int r = 0; r < 4; ++r) pmax = fmaxf(pmax, st[f][r]);
                pmax = fmaxf(pmax, __shfl_xor(pmax, 16));
                pmax = fmaxf(pmax, __shfl_xor(pmax, 32));
                float mnew = fmaxf(mrun, pmax);
                float corr = __builtin_amdgcn_exp2f(mrun - mnew);
                float psum = 0.f;
#pragma unroll
                for (int f = 0; f < 4; ++f) {
                    u16x4 pk;
#pragma unroll
                    for (int r = 0; r < 4; ++r) {
                        float p = __builtin_amdgcn_exp2f(st[f][r] - mnew);
                        psum += p;
                        pk[r] = f2bf(p);
                    }
                    *(u16x4*)&P[w][ql][f * 16 + g * 4] = pk;  // b64 write
                }
                psum += __shfl_xor(psum, 16);
                psum += __shfl_xor(psum, 32);
                lrun = lrun * corr + psum;
#pragma unroll
                for (int f = 0; f < 4; ++f) ot[f] *= corr;
                mrun = mnew;
                // wave-internal cross-lane LDS visibility (no barrier needed)
                asm volatile("s_waitcnt lgkmcnt(0)" ::: "memory");
#pragma unroll
                for (int dc = 0; dc < 2; ++dc) {
                    bf16x8 pf = *(const bf16x8*)&P[w][ql][dc * 32 + g * 8];  // b128 read
                    __builtin_amdgcn_s_setprio(1);
#pragma unroll
                    for (int f = 0; f < 4; ++f) {
                        int rv = f * 16 + ql, sw = rv & 7;
                        bf16x8 vf = *(const bf16x8*)&Vtl[rv * 64 + (((dc * 4 + g) ^ sw) * 8)];
                        ot[f] = __builtin_amdgcn_mfma_f32_16x16x32_bf16(vf, pf, ot[f], 0, 0, 0);
                    }
                    __builtin_amdgcn_s_setprio(0);
                }
            }
            asm volatile("s_waitcnt vmcnt(0)" ::: "memory");  // prefetch landed
            __syncthreads();                                   // all waves: buf ready / done
            cur ^= 1;
        }
        float inv = 1.f / lrun;
        unsigned short* ap = att + ((size_t)(b * 2048 + qg)) * 1024 + h * 64;
#pragma unroll
        for (int f = 0; f < 4; ++f) {
            u16x4 o;
#pragma unroll
            for (int r = 0; r < 4; ++r) o[r] = f2bf(ot[f][r] * inv);
            *(u16x4*)&ap[f * 16 + g * 4] = o;
        }
        // next phase's first STAGE is safe: all reads of both buffers completed
        // before this phase's final barrier.
    }
#undef ATT_STAGE
}

extern "C" void kernel_launch(void* const* d_in, const int* in_sizes, int n_in,
                              void* d_out, int out_size, void* d_ws, size_t ws_size,
                              hipStream_t stream) {
    const float* x = (const float*)d_in[0];
    const float* wq = (const float*)d_in[2];
    const float* wk = (const float*)d_in[3];
    const float* wv = (const float*)d_in[4];
    const float* wproj = (const float*)d_in[5];
    const float* bproj = (const float*)d_in[6];
    float* out = (float*)d_out;

    char* ws = (char*)d_ws;
    unsigned short* xb     = (unsigned short*)(ws);               // 8 MB [4096][1024]
    unsigned short* WqkvT  = (unsigned short*)(ws + (8u << 20));  // 6 MB [3072][1024]
    unsigned short* WprojT = (unsigned short*)(ws + (14u << 20)); // 2 MB [1024][1024]
    unsigned short* Qb     = (unsigned short*)(ws + (16u << 20)); // 8 MB [32][2048][64]
    unsigned short* Kb     = (unsigned short*)(ws + (24u << 20)); // 8 MB [32][2048][64]
    unsigned short* Vt     = (unsigned short*)(ws + (32u << 20)); // 8 MB [32][64][2048]
    unsigned short* att    = xb;  // reuse: xb dead after gemm1   // 8 MB [4096][1024]

    k_cast<<<2048, 256, 0, stream>>>(x, xb);
    k_transw<<<dim3(16, 1, 16), 256, 0, stream>>>(wq, WqkvT, 64, 1024 * 64, 0, 64);
    k_transw<<<dim3(16, 1, 16), 256, 0, stream>>>(wk, WqkvT, 64, 1024 * 64, 1024, 64);
    k_transw<<<dim3(16, 1, 16), 256, 0, stream>>>(wv, WqkvT, 64, 1024 * 64, 2048, 64);
    k_transw<<<dim3(16, 16, 1), 256, 0, stream>>>(wproj, WprojT, 1024, 0, 0, 0);
    k_gemm<1><<<dim3(24, 32), 256, 0, stream>>>(xb, WqkvT, 1024, nullptr, nullptr, Qb, Kb, Vt);
    k_attn<<<dim3(8, 32), 512, 0, stream>>>(Qb, Kb, Vt, att);
    k_gemm<3><<<dim3(8, 32), 256, 0, stream>>>(att, WprojT, 1024, out, bproj, nullptr, nullptr, nullptr);
}